// Round 2
// baseline (135.155 us; speedup 1.0000x reference)
//
#include <hip/hip_runtime.h>
#include <hip/hip_bf16.h>

// out[b,i,j] = sqrt(sum_k (coords[b,j,k] - coords[b,i,k])^2)
// coords: [B=8][N=2048][3] f32, out: [B][N][N] f32.
// Write-BW bound: 134 MB out, 196 KB in (cache-resident).

#define N_PTS 2048

__global__ __launch_bounds__(256) void coord_to_dist_kernel(
    const float* __restrict__ coords, float* __restrict__ out) {
    // One block per (b, i) row. 256 threads x 2 iters x float4 = 2048 outputs.
    const int bi = blockIdx.x;          // 0 .. B*N-1
    const int b  = bi >> 11;            // / 2048
    const int i  = bi & (N_PTS - 1);

    const float* cb = coords + (size_t)b * N_PTS * 3;
    const float xi = cb[i * 3 + 0];
    const float yi = cb[i * 3 + 1];
    const float zi = cb[i * 3 + 2];

    float* orow = out + (size_t)bi * N_PTS;
    const int t = threadIdx.x;

#pragma unroll
    for (int r = 0; r < 2; ++r) {
        const int j0 = (t + (r << 8)) << 2;   // 4-aligned column start
        // 4 points = 12 contiguous floats = 3 aligned float4 loads
        const float4* p = reinterpret_cast<const float4*>(cb + (size_t)j0 * 3);
        const float4 a = p[0];   // x0 y0 z0 x1
        const float4 c = p[1];   // y1 z1 x2 y2
        const float4 e = p[2];   // z2 x3 y3 z3

        float4 v;
        {
            const float dx = a.x - xi, dy = a.y - yi, dz = a.z - zi;
            v.x = sqrtf(dx * dx + dy * dy + dz * dz);
        }
        {
            const float dx = a.w - xi, dy = c.x - yi, dz = c.y - zi;
            v.y = sqrtf(dx * dx + dy * dy + dz * dz);
        }
        {
            const float dx = c.z - xi, dy = c.w - yi, dz = e.x - zi;
            v.z = sqrtf(dx * dx + dy * dy + dz * dz);
        }
        {
            const float dx = e.y - xi, dy = e.z - yi, dz = e.w - zi;
            v.w = sqrtf(dx * dx + dy * dy + dz * dz);
        }
        *reinterpret_cast<float4*>(orow + j0) = v;
    }
}

extern "C" void kernel_launch(void* const* d_in, const int* in_sizes, int n_in,
                              void* d_out, int out_size, void* d_ws, size_t ws_size,
                              hipStream_t stream) {
    const float* coords = (const float*)d_in[0];
    float* out = (float*)d_out;
    // B*N = 8 * 2048 = 16384 blocks
    coord_to_dist_kernel<<<16384, 256, 0, stream>>>(coords, out);
}

// Round 5
// 134.292 us; speedup vs baseline: 1.0064x; 1.0064x over previous
//
#include <hip/hip_runtime.h>
#include <hip/hip_bf16.h>

// out[b,i,j] = sqrt(sum_k (coords[b,j,k] - coords[b,i,k])^2)
// coords: [B=8][N=2048][3] f32, out: [B][N][N] f32 (symmetric -> no transpose risk).
// Write-BW bound: 134 MB out. Tile 16 i-rows/block so j-coords load once into
// registers; stores are fully lane-contiguous float4 (1 KB/instr per wave).

#define N_PTS 2048
#define ROWS  16   // i-rows per block; grid = 8 * (2048/16) = 1024 blocks

__global__ __launch_bounds__(256) void coord_to_dist_kernel(
    const float* __restrict__ coords, float* __restrict__ out) {
    const int blk = blockIdx.x;            // 0..1023
    const int b   = blk >> 7;              // 128 blocks per batch
    const int i0  = (blk & 127) * ROWS;

    const float* cb = coords + (size_t)b * N_PTS * 3;
    const int t = threadIdx.x;

    // Thread t owns j = 4t..4t+3  and  j = 1024+4t..1024+4t+3.
    // Load those 8 points' coords (2 x 48 B) once per block.
    const float4* pA = reinterpret_cast<const float4*>(cb + (size_t)(4 * t) * 3);
    const float4* pB = reinterpret_cast<const float4*>(cb + (size_t)(1024 + 4 * t) * 3);
    const float4 a0 = pA[0], a1 = pA[1], a2 = pA[2];
    const float4 b0 = pB[0], b1 = pB[1], b2 = pB[2];

    float jx[8], jy[8], jz[8];
    jx[0] = a0.x; jy[0] = a0.y; jz[0] = a0.z;
    jx[1] = a0.w; jy[1] = a1.x; jz[1] = a1.y;
    jx[2] = a1.z; jy[2] = a1.w; jz[2] = a2.x;
    jx[3] = a2.y; jy[3] = a2.z; jz[3] = a2.w;
    jx[4] = b0.x; jy[4] = b0.y; jz[4] = b0.z;
    jx[5] = b0.w; jy[5] = b1.x; jz[5] = b1.y;
    jx[6] = b1.z; jy[6] = b1.w; jz[6] = b2.x;
    jx[7] = b2.y; jy[7] = b2.z; jz[7] = b2.w;

    float* ob = out + ((size_t)b * N_PTS + i0) * N_PTS;

#pragma unroll
    for (int r = 0; r < ROWS; ++r) {
        // Block-uniform i-coords -> scalar loads, cache-resident.
        const float xi = cb[(i0 + r) * 3 + 0];
        const float yi = cb[(i0 + r) * 3 + 1];
        const float zi = cb[(i0 + r) * 3 + 2];

        float o[8];
#pragma unroll
        for (int u = 0; u < 8; ++u) {
            const float dx = jx[u] - xi;
            const float dy = jy[u] - yi;
            const float dz = jz[u] - zi;
            o[u] = sqrtf(dx * dx + dy * dy + dz * dz);
        }

        float* orow = ob + (size_t)r * N_PTS;
        // Lane-contiguous: lane t writes [16t,16t+16) -> 1 KB/wave/instr.
        *reinterpret_cast<float4*>(orow + 4 * t)        = make_float4(o[0], o[1], o[2], o[3]);
        *reinterpret_cast<float4*>(orow + 1024 + 4 * t) = make_float4(o[4], o[5], o[6], o[7]);
    }
}

extern "C" void kernel_launch(void* const* d_in, const int* in_sizes, int n_in,
                              void* d_out, int out_size, void* d_ws, size_t ws_size,
                              hipStream_t stream) {
    const float* coords = (const float*)d_in[0];
    float* out = (float*)d_out;
    coord_to_dist_kernel<<<8 * (N_PTS / ROWS), 256, 0, stream>>>(coords, out);
}